// Round 12
// baseline (343.076 us; speedup 1.0000x reference)
//
#include <hip/hip_runtime.h>
#include <math.h>

#define D 64              // feature dim (both layers)
#define SCAN_BLOCK 256
#define SCAN_ITEMS 4      // cnt elements per thread
#define SCAN_TILE (SCAN_BLOCK * SCAN_ITEMS)   // 1024 per block
#define NREG 8            // XCD-aligned regions for atomic-heavy kernels
#define FILL_CHUNK 4096   // edges per chunk in regionized kernels

// bf16 helpers (manual, RTNE encode / shift decode)
__device__ __forceinline__ unsigned short f2bf(float f) {
    union { float f; unsigned int i; } v; v.f = f;
    unsigned int u = v.i;
    unsigned int r = (u + 0x7FFFu + ((u >> 16) & 1u)) >> 16;   // round-to-nearest-even
    return (unsigned short)r;
}
__device__ __forceinline__ float bf2f(unsigned short u) {
    union { unsigned int i; float f; } v; v.i = ((unsigned int)u) << 16;
    return v.f;
}

// ---------------- zero int buffer ----------------
__global__ void zero_int_kernel(int* p, int n) {
    int i = blockIdx.x * blockDim.x + threadIdx.x;
    if (i < n) p[i] = 0;
}

// ---------------- regionized in-degree count ----------------
// nt load on the col stream: don't let the 4MB/XCD stream evict the dirty
// cnt lines that the atomics are accumulating into.
__global__ void count_region_kernel(const int* __restrict__ col, int* cnt, int E, int n) {
    int r = blockIdx.x & (NREG - 1);
    int c = blockIdx.x >> 3;
    int lo = (int)(((long long)r * n) / NREG);
    int hi = (int)(((long long)(r + 1) * n) / NREG);
    int e0 = c * FILL_CHUNK;
    int e1 = min(E, e0 + FILL_CHUNK);
    for (int e = e0 + (int)threadIdx.x; e < e1; e += (int)blockDim.x) {
        int cl = __builtin_nontemporal_load(col + e);
        if (cl >= lo && cl < hi) atomicAdd(&cnt[cl], 1);
    }
}

// ---------------- 3-phase device-wide exclusive scan ----------------
__global__ void block_reduce_kernel(const int* __restrict__ cnt, int* __restrict__ blockSums, int n) {
    int b = blockIdx.x, t = threadIdx.x;
    int base = b * SCAN_TILE + t * SCAN_ITEMS;
    int s = 0;
    #pragma unroll
    for (int k = 0; k < SCAN_ITEMS; ++k) {
        int i = base + k;
        if (i < n) s += cnt[i];
    }
    #pragma unroll
    for (int o = 32; o > 0; o >>= 1) s += __shfl_xor(s, o, 64);
    __shared__ int wsum[SCAN_BLOCK / 64];
    if ((t & 63) == 0) wsum[t >> 6] = s;
    __syncthreads();
    if (t == 0) {
        int tot = 0;
        #pragma unroll
        for (int w = 0; w < SCAN_BLOCK / 64; ++w) tot += wsum[w];
        blockSums[b] = tot;
    }
}

__global__ void scan_sums_kernel(int* blockSums, int nb) {
    __shared__ int sh[256];
    int t = threadIdx.x;
    int v = (t < nb) ? blockSums[t] : 0;
    sh[t] = v;
    __syncthreads();
    for (int o = 1; o < 256; o <<= 1) {
        int u = (t >= o) ? sh[t - o] : 0;
        __syncthreads();
        sh[t] += u;
        __syncthreads();
    }
    if (t < nb) blockSums[t] = (t == 0) ? 0 : sh[t - 1];   // exclusive base per block
}

__global__ void scan_apply_kernel(const int* __restrict__ cnt, const int* __restrict__ blockSums,
                                  int* __restrict__ off, float* __restrict__ dinv, int n) {
    int b = blockIdx.x, t = threadIdx.x;
    int base = b * SCAN_TILE + t * SCAN_ITEMS;
    int c[SCAN_ITEMS];
    int s = 0;
    #pragma unroll
    for (int k = 0; k < SCAN_ITEMS; ++k) {
        int i = base + k;
        c[k] = (i < n) ? cnt[i] : 0;
        s += c[k];
    }
    __shared__ int sh[SCAN_BLOCK];
    sh[t] = s;
    __syncthreads();
    for (int o = 1; o < SCAN_BLOCK; o <<= 1) {
        int u = (t >= o) ? sh[t - o] : 0;
        __syncthreads();
        sh[t] += u;
        __syncthreads();
    }
    int run = blockSums[b] + ((t == 0) ? 0 : sh[t - 1]);
    #pragma unroll
    for (int k = 0; k < SCAN_ITEMS; ++k) {
        int i = base + k;
        if (i < n) {
            off[i] = run;            // exclusive start (fill converts to inclusive end)
            run += c[k];
            dinv[i] = rsqrtf(1.0f + (float)c[k]);
        }
    }
}

// ---------------- region boundaries ----------------
__global__ void region_bounds_kernel(const int* __restrict__ off, int* __restrict__ colBound,
                                     int n, int E) {
    int k = threadIdx.x;
    if (k > NREG) return;
    if (k == 0) { colBound[0] = 0; return; }
    if (k == NREG) { colBound[NREG] = n; return; }
    long long target = ((long long)k * E) / NREG;
    int lo = 0, hi = n;
    while (lo < hi) {
        int mid = (lo + hi) >> 1;
        if ((long long)off[mid] < target) lo = mid + 1; else hi = mid;
    }
    colBound[k] = lo;
}

// ---------------- regionized CSR fill ----------------
// nt loads on the col/row streams; dirty adj/off lines stay resident in the
// region's XCD L2 until fully populated -> ~1 writeback per line.
__global__ void fill_region_kernel(const int* __restrict__ row, const int* __restrict__ col,
                                   const int* __restrict__ colBound,
                                   int* off, int* __restrict__ adj, int E) {
    int r = blockIdx.x & (NREG - 1);
    int c = blockIdx.x >> 3;
    int lo = colBound[r], hi = colBound[r + 1];
    int e0 = c * FILL_CHUNK;
    int e1 = min(E, e0 + FILL_CHUNK);
    for (int e = e0 + (int)threadIdx.x; e < e1; e += (int)blockDim.x) {
        int cl = __builtin_nontemporal_load(col + e);
        if (cl >= lo && cl < hi) {
            int rw = __builtin_nontemporal_load(row + e);
            int pos = atomicAdd(&off[cl], 1);
            adj[pos] = rw;
        }
    }
}

// ---------------- dense GEMM: Ybf16[n,64] = act(X[n,64]) @ W[64,64] ----------------
__device__ __forceinline__ float4 fma4(float s, float4 w, float4 a) {
    a.x = fmaf(s, w.x, a.x); a.y = fmaf(s, w.y, a.y);
    a.z = fmaf(s, w.z, a.z); a.w = fmaf(s, w.w, a.w);
    return a;
}

__global__ void gemm64_reg_kernel(const float* __restrict__ X, const float* __restrict__ W,
                                  unsigned short* __restrict__ Y, int n, int applyRelu) {
    int gtid = blockIdx.x * blockDim.x + threadIdx.x;
    int wv = gtid >> 6;                         // global wave id
    int nw = (gridDim.x * blockDim.x) >> 6;     // total waves
    int lane = threadIdx.x & 63;
    int c4 = lane & 15;
    int kg = lane >> 4;

    float4 wreg[16];
    #pragma unroll
    for (int t = 0; t < 16; ++t)
        wreg[t] = ((const float4*)W)[(kg * 16 + t) * 16 + c4];

    for (int r = wv; r < n; r += nw) {
        const float4* xr = (const float4*)(X + (size_t)r * D) + kg * 4;
        float4 acc = make_float4(0.f, 0.f, 0.f, 0.f);
        #pragma unroll
        for (int t4 = 0; t4 < 4; ++t4) {
            float4 xv = xr[t4];
            if (applyRelu) {
                xv.x = fmaxf(xv.x, 0.f); xv.y = fmaxf(xv.y, 0.f);
                xv.z = fmaxf(xv.z, 0.f); xv.w = fmaxf(xv.w, 0.f);
            }
            acc = fma4(xv.x, wreg[t4 * 4 + 0], acc);
            acc = fma4(xv.y, wreg[t4 * 4 + 1], acc);
            acc = fma4(xv.z, wreg[t4 * 4 + 2], acc);
            acc = fma4(xv.w, wreg[t4 * 4 + 3], acc);
        }
        acc.x += __shfl_xor(acc.x, 16, 64); acc.y += __shfl_xor(acc.y, 16, 64);
        acc.z += __shfl_xor(acc.z, 16, 64); acc.w += __shfl_xor(acc.w, 16, 64);
        acc.x += __shfl_xor(acc.x, 32, 64); acc.y += __shfl_xor(acc.y, 32, 64);
        acc.z += __shfl_xor(acc.z, 32, 64); acc.w += __shfl_xor(acc.w, 32, 64);
        if (lane < 16) {
            ushort4 o;
            o.x = f2bf(acc.x); o.y = f2bf(acc.y);
            o.z = f2bf(acc.z); o.w = f2bf(acc.w);
            ((ushort4*)(Y + (size_t)r * D))[c4] = o;   // 8B per lane, 128B per row
        }
    }
}

// ---------------- pull aggregation: one wave per node, bf16 gather payload ----------------
template <int DOTS>
__global__ void agg_kernel(const unsigned short* __restrict__ xw, const float* __restrict__ dinv,
                           const int* __restrict__ off, const int* __restrict__ adj,
                           const float* __restrict__ b, float* __restrict__ out,
                           const float* __restrict__ wlin,
                           float* __restrict__ adot, float* __restrict__ bdot, int n) {
    int wid = blockIdx.x * 4 + (threadIdx.x >> 6);
    if (wid >= n) return;
    int lane = threadIdx.x & 63;
    int l = lane & 15;      // 4-dim chunk of the row
    int g = lane >> 4;      // neighbor slot group 0..3
    int start = (wid == 0) ? 0 : off[wid - 1];
    int end = off[wid];
    int deg = end - start;
    float di = dinv[wid];
    const ushort4* xwb = (const ushort4*)xw;   // row stride = 16 ushort4

    float4 acc = make_float4(0.f, 0.f, 0.f, 0.f);
    if (g == 0) {           // self-loop + bias, added once
        ushort4 u = xwb[(size_t)wid * 16 + l];
        float4 bb = ((const float4*)b)[l];
        float s = di * di;
        acc.x = fmaf(bf2f(u.x), s, bb.x); acc.y = fmaf(bf2f(u.y), s, bb.y);
        acc.z = fmaf(bf2f(u.z), s, bb.z); acc.w = fmaf(bf2f(u.w), s, bb.w);
    }

    for (int base = 0; base < deg; base += 64) {
        // phase 1: cooperative index+scale prefetch (uniform flow before shfl)
        int k = base + lane;
        int a = 0; float s = 0.f;
        if (k < deg) {
            a = adj[start + k];          // coalesced 256B wave load
            s = dinv[a] * di;            // one 4B gather per lane
        }
        int m = min(64, deg - base);
        int mm = (m + 7) & ~7;           // wave-uniform padded bound
        // phase 2: uniform trip count; two independent 128B row gathers per iter
        for (int kk = g; kk < mm; kk += 8) {
            int r0 = __shfl(a, kk, 64);
            int r1 = __shfl(a, kk + 4, 64);
            float s0 = __shfl(s, kk, 64);
            float s1 = __shfl(s, kk + 4, 64);
            ushort4 u0 = xwb[(size_t)r0 * 16 + l];
            ushort4 u1 = xwb[(size_t)r1 * 16 + l];
            acc.x = fmaf(bf2f(u0.x), s0, acc.x); acc.y = fmaf(bf2f(u0.y), s0, acc.y);
            acc.z = fmaf(bf2f(u0.z), s0, acc.z); acc.w = fmaf(bf2f(u0.w), s0, acc.w);
            acc.x = fmaf(bf2f(u1.x), s1, acc.x); acc.y = fmaf(bf2f(u1.y), s1, acc.y);
            acc.z = fmaf(bf2f(u1.z), s1, acc.z); acc.w = fmaf(bf2f(u1.w), s1, acc.w);
        }
    }
    // reduce across the 4 neighbor-slot groups
    acc.x += __shfl_xor(acc.x, 16, 64); acc.y += __shfl_xor(acc.y, 16, 64);
    acc.z += __shfl_xor(acc.z, 16, 64); acc.w += __shfl_xor(acc.w, 16, 64);
    acc.x += __shfl_xor(acc.x, 32, 64); acc.y += __shfl_xor(acc.y, 32, 64);
    acc.z += __shfl_xor(acc.z, 32, 64); acc.w += __shfl_xor(acc.w, 32, 64);

    if (DOTS) {
        float4 hv = acc;
        hv.x = fmaxf(hv.x, 0.f); hv.y = fmaxf(hv.y, 0.f);
        hv.z = fmaxf(hv.z, 0.f); hv.w = fmaxf(hv.w, 0.f);
        float4 wa = ((const float4*)wlin)[l];
        float4 wb = ((const float4*)wlin)[16 + l];
        float pa = hv.x * wa.x + hv.y * wa.y + hv.z * wa.z + hv.w * wa.w;
        float pb = hv.x * wb.x + hv.y * wb.y + hv.z * wb.z + hv.w * wb.w;
        #pragma unroll
        for (int o = 8; o > 0; o >>= 1) {
            pa += __shfl_xor(pa, o, 64);
            pb += __shfl_xor(pb, o, 64);
        }
        if (lane == 0) { adot[wid] = pa; bdot[wid] = pb; }
    } else {
        if (lane < 16)
            ((float4*)(out + (size_t)wid * D))[l] = acc;
    }
}

// ---------------- edge output: sigmoid(adot[row] + bdot[col] + blin) ----------------
__global__ void edge_out_kernel(const int* __restrict__ row, const int* __restrict__ col,
                                const float* __restrict__ adot, const float* __restrict__ bdot,
                                const float* __restrict__ blin, float* __restrict__ out, int E) {
    int e = blockIdx.x * blockDim.x + threadIdx.x;
    if (e >= E) return;
    float z = adot[row[e]] + bdot[col[e]] + blin[0];
    out[e] = 1.f / (1.f + expf(-z));
}

// ---------------- launch ----------------
extern "C" void kernel_launch(void* const* d_in, const int* in_sizes, int n_in,
                              void* d_out, int out_size, void* d_ws, size_t ws_size,
                              hipStream_t stream) {
    const float* x     = (const float*)d_in[0];
    const int*   ei    = (const int*)d_in[1];
    const float* w1    = (const float*)d_in[2];
    const float* b1    = (const float*)d_in[3];
    const float* w2    = (const float*)d_in[4];
    const float* b2    = (const float*)d_in[5];
    const float* w_lin = (const float*)d_in[6];
    const float* b_lin = (const float*)d_in[7];
    float* out = (float*)d_out;

    int n = in_sizes[0] / D;        // 100000
    int E = in_sizes[1] / 2;        // 1000000
    const int* row = ei;
    const int* col = ei + E;

    // ---- workspace bump allocator (256B aligned) ----
    char* ws = (char*)d_ws;
    size_t cur = 0;
    auto alloc = [&](size_t bytes) -> void* {
        void* p = ws + cur;
        cur += (bytes + 255) / 256 * 256;
        return p;
    };
    int nScanBlocks = (n + SCAN_TILE - 1) / SCAN_TILE;   // 98 for n=100000 (<=256)
    int*            cnt    = (int*)   alloc((size_t)n * sizeof(int));
    int*            off    = (int*)   alloc((size_t)n * sizeof(int));
    float*          dinv   = (float*) alloc((size_t)n * sizeof(float));
    int*            bsums  = (int*)   alloc((size_t)nScanBlocks * sizeof(int));
    int*            cbound = (int*)   alloc((size_t)(NREG + 1) * sizeof(int));
    int*            adj    = (int*)   alloc((size_t)E * sizeof(int));
    float*          adot   = (float*) alloc((size_t)n * sizeof(float));
    float*          bdot   = (float*) alloc((size_t)n * sizeof(float));
    unsigned short* bufA   = (unsigned short*)alloc((size_t)n * D * sizeof(unsigned short)); // xw bf16
    float*          bufB   = (float*) alloc((size_t)n * D * sizeof(float));                  // h1 f32

    const int BT = 256;
    int gN     = (n + BT - 1) / BT;
    int gE     = (E + BT - 1) / BT;
    int gWave  = (n + 3) / 4;                     // 4 waves (nodes) per block
    int gGemm  = 1024;                            // grid-stride GEMM
    int nChunk = (E + FILL_CHUNK - 1) / FILL_CHUNK;
    int gReg   = nChunk * NREG;

    // ---- CSR build + normalization ----
    zero_int_kernel<<<gN, BT, 0, stream>>>(cnt, n);
    count_region_kernel<<<gReg, BT, 0, stream>>>(col, cnt, E, n);
    block_reduce_kernel<<<nScanBlocks, SCAN_BLOCK, 0, stream>>>(cnt, bsums, n);
    scan_sums_kernel<<<1, 256, 0, stream>>>(bsums, nScanBlocks);
    scan_apply_kernel<<<nScanBlocks, SCAN_BLOCK, 0, stream>>>(cnt, bsums, off, dinv, n);
    region_bounds_kernel<<<1, 64, 0, stream>>>(off, cbound, n, E);
    fill_region_kernel<<<gReg, BT, 0, stream>>>(row, col, cbound, off, adj, E);
    // off[i] now = inclusive end of node i's adjacency; start = off[i-1] (0 for i=0)

    // ---- layer 1: h1 = agg(x @ w1) + b1  (relu deferred to next load) ----
    gemm64_reg_kernel<<<gGemm, BT, 0, stream>>>(x, w1, bufA, n, 0);
    agg_kernel<0><<<gWave, BT, 0, stream>>>(bufA, dinv, off, adj, b1, bufB,
                                            nullptr, nullptr, nullptr, n);

    // ---- layer 2: xw2 = relu(h1) @ w2; agg fused with edge-head node dots ----
    gemm64_reg_kernel<<<gGemm, BT, 0, stream>>>(bufB, w2, bufA, n, 1);
    agg_kernel<1><<<gWave, BT, 0, stream>>>(bufA, dinv, off, adj, b2, nullptr,
                                            w_lin, adot, bdot, n);

    // ---- edge prediction head ----
    edge_out_kernel<<<gE, BT, 0, stream>>>(row, col, adot, bdot, b_lin, out, E);
}

// Round 13
// 276.048 us; speedup vs baseline: 1.2428x; 1.2428x over previous
//
#include <hip/hip_runtime.h>
#include <math.h>

#define D 64              // feature dim (both layers)
#define SCAN_BLOCK 256
#define SCAN_ITEMS 4      // elements per thread in device-wide scan
#define SCAN_TILE (SCAN_BLOCK * SCAN_ITEMS)   // 1024 per block
#define NB_SHIFT 9        // 512 nodes per bucket

// bf16 helpers (manual, RTNE encode / shift decode)
__device__ __forceinline__ unsigned short f2bf(float f) {
    union { float f; unsigned int i; } v; v.f = f;
    unsigned int u = v.i;
    unsigned int r = (u + 0x7FFFu + ((u >> 16) & 1u)) >> 16;   // round-to-nearest-even
    return (unsigned short)r;
}
__device__ __forceinline__ float bf2f(unsigned short u) {
    union { unsigned int i; float f; } v; v.i = ((unsigned int)u) << 16;
    return v.f;
}

// ---------------- K1: per-chunk bucket histogram (LDS only, no global atomics) ----------------
// histG layout: [bucket][block]  (bucket-major for the bucket-major scan)
__global__ void hist_kernel(const int* __restrict__ col, int* __restrict__ histG,
                            int E, int B, int NB, int CH) {
    __shared__ int h[512];
    int b = blockIdx.x, t = threadIdx.x;
    for (int i = t; i < NB; i += blockDim.x) h[i] = 0;
    __syncthreads();
    int e0 = b * CH, e1 = min(E, e0 + CH);
    for (int e = e0 + t; e < e1; e += blockDim.x) {
        int c = __builtin_nontemporal_load(col + e);
        atomicAdd(&h[c >> NB_SHIFT], 1);      // LDS atomic
    }
    __syncthreads();
    for (int i = t; i < NB; i += blockDim.x) histG[i * B + b] = h[i];
}

// ---------------- 3-phase device-wide exclusive scan (generic) ----------------
__global__ void block_reduce_kernel(const int* __restrict__ cnt, int* __restrict__ blockSums, int n) {
    int b = blockIdx.x, t = threadIdx.x;
    int base = b * SCAN_TILE + t * SCAN_ITEMS;
    int s = 0;
    #pragma unroll
    for (int k = 0; k < SCAN_ITEMS; ++k) {
        int i = base + k;
        if (i < n) s += cnt[i];
    }
    #pragma unroll
    for (int o = 32; o > 0; o >>= 1) s += __shfl_xor(s, o, 64);
    __shared__ int wsum[SCAN_BLOCK / 64];
    if ((t & 63) == 0) wsum[t >> 6] = s;
    __syncthreads();
    if (t == 0) {
        int tot = 0;
        #pragma unroll
        for (int w = 0; w < SCAN_BLOCK / 64; ++w) tot += wsum[w];
        blockSums[b] = tot;
    }
}

__global__ void scan_sums_kernel(int* blockSums, int nb) {
    __shared__ int sh[256];
    int t = threadIdx.x;
    int v = (t < nb) ? blockSums[t] : 0;
    sh[t] = v;
    __syncthreads();
    for (int o = 1; o < 256; o <<= 1) {
        int u = (t >= o) ? sh[t - o] : 0;
        __syncthreads();
        sh[t] += u;
        __syncthreads();
    }
    if (t < nb) blockSums[t] = (t == 0) ? 0 : sh[t - 1];   // exclusive base per block
}

// writes outArr[i] = exclusive prefix sum; dinv optional (unused for histogram scan)
__global__ void scan_apply_kernel(const int* __restrict__ cnt, const int* __restrict__ blockSums,
                                  int* __restrict__ outArr, float* __restrict__ dinv, int n) {
    int b = blockIdx.x, t = threadIdx.x;
    int base = b * SCAN_TILE + t * SCAN_ITEMS;
    int c[SCAN_ITEMS];
    int s = 0;
    #pragma unroll
    for (int k = 0; k < SCAN_ITEMS; ++k) {
        int i = base + k;
        c[k] = (i < n) ? cnt[i] : 0;
        s += c[k];
    }
    __shared__ int sh[SCAN_BLOCK];
    sh[t] = s;
    __syncthreads();
    for (int o = 1; o < SCAN_BLOCK; o <<= 1) {
        int u = (t >= o) ? sh[t - o] : 0;
        __syncthreads();
        sh[t] += u;
        __syncthreads();
    }
    int run = blockSums[b] + ((t == 0) ? 0 : sh[t - 1]);
    #pragma unroll
    for (int k = 0; k < SCAN_ITEMS; ++k) {
        int i = base + k;
        if (i < n) {
            outArr[i] = run;
            run += c[k];
            if (dinv) dinv[i] = rsqrtf(1.0f + (float)c[k]);
        }
    }
}

// ---------------- K3: partition edges into bucket runs (LDS cursors) ----------------
__global__ void scatter_pairs_kernel(const int* __restrict__ row, const int* __restrict__ col,
                                     const int* __restrict__ scanH, int2* __restrict__ pairs,
                                     int E, int B, int NB, int CH) {
    __shared__ int cur[512];
    int b = blockIdx.x, t = threadIdx.x;
    for (int i = t; i < NB; i += blockDim.x) cur[i] = scanH[i * B + b];
    __syncthreads();
    int e0 = b * CH, e1 = min(E, e0 + CH);
    for (int e = e0 + t; e < e1; e += blockDim.x) {
        int c = __builtin_nontemporal_load(col + e);
        int r = __builtin_nontemporal_load(row + e);
        int pos = atomicAdd(&cur[c >> NB_SHIFT], 1);   // LDS atomic
        pairs[pos] = make_int2(r, c);                  // ~160B runs per cursor
    }
}

// ---------------- K4: per-bucket counting sort -> off (inclusive end), dinv, adj ----------------
__global__ void bucket_csr_kernel(const int2* __restrict__ pairs, const int* __restrict__ scanH,
                                  int* __restrict__ off, float* __restrict__ dinv,
                                  int* __restrict__ adj, int E, int B, int NB, int n) {
    __shared__ int cnt[512];
    __shared__ int curs[512];
    __shared__ int psum[256];
    int k = blockIdx.x, t = threadIdx.x;
    int nodeBase = k << NB_SHIFT;
    int eStart = scanH[k * B];
    int eEnd = (k == NB - 1) ? E : scanH[(k + 1) * B];
    cnt[t] = 0; cnt[t + 256] = 0;
    __syncthreads();
    for (int e = eStart + t; e < eEnd; e += 256)
        atomicAdd(&cnt[pairs[e].y - nodeBase], 1);     // LDS atomic
    __syncthreads();
    int c0 = cnt[2 * t], c1 = cnt[2 * t + 1];
    psum[t] = c0 + c1;
    __syncthreads();
    for (int o = 1; o < 256; o <<= 1) {
        int u = (t >= o) ? psum[t - o] : 0;
        __syncthreads();
        psum[t] += u;
        __syncthreads();
    }
    int base = (t == 0) ? 0 : psum[t - 1];
    int node0 = nodeBase + 2 * t, node1 = node0 + 1;
    if (node0 < n) { off[node0] = eStart + base + c0;      dinv[node0] = rsqrtf(1.0f + (float)c0); }
    if (node1 < n) { off[node1] = eStart + base + c0 + c1; dinv[node1] = rsqrtf(1.0f + (float)c1); }
    curs[2 * t]     = eStart + base;           // exclusive starts
    curs[2 * t + 1] = eStart + base + c0;
    __syncthreads();
    for (int e = eStart + t; e < eEnd; e += 256) {
        int2 p = pairs[e];
        int pos = atomicAdd(&curs[p.y - nodeBase], 1);  // LDS atomic
        adj[pos] = p.x;                                 // 4B scatter within ~20KB window
    }
}

// ---------------- dense GEMM: Ybf16[n,64] = act(X[n,64]) @ W[64,64] ----------------
__device__ __forceinline__ float4 fma4(float s, float4 w, float4 a) {
    a.x = fmaf(s, w.x, a.x); a.y = fmaf(s, w.y, a.y);
    a.z = fmaf(s, w.z, a.z); a.w = fmaf(s, w.w, a.w);
    return a;
}

__global__ void gemm64_reg_kernel(const float* __restrict__ X, const float* __restrict__ W,
                                  unsigned short* __restrict__ Y, int n, int applyRelu) {
    int gtid = blockIdx.x * blockDim.x + threadIdx.x;
    int wv = gtid >> 6;                         // global wave id
    int nw = (gridDim.x * blockDim.x) >> 6;     // total waves
    int lane = threadIdx.x & 63;
    int c4 = lane & 15;
    int kg = lane >> 4;

    float4 wreg[16];
    #pragma unroll
    for (int t = 0; t < 16; ++t)
        wreg[t] = ((const float4*)W)[(kg * 16 + t) * 16 + c4];

    for (int r = wv; r < n; r += nw) {
        const float4* xr = (const float4*)(X + (size_t)r * D) + kg * 4;
        float4 acc = make_float4(0.f, 0.f, 0.f, 0.f);
        #pragma unroll
        for (int t4 = 0; t4 < 4; ++t4) {
            float4 xv = xr[t4];
            if (applyRelu) {
                xv.x = fmaxf(xv.x, 0.f); xv.y = fmaxf(xv.y, 0.f);
                xv.z = fmaxf(xv.z, 0.f); xv.w = fmaxf(xv.w, 0.f);
            }
            acc = fma4(xv.x, wreg[t4 * 4 + 0], acc);
            acc = fma4(xv.y, wreg[t4 * 4 + 1], acc);
            acc = fma4(xv.z, wreg[t4 * 4 + 2], acc);
            acc = fma4(xv.w, wreg[t4 * 4 + 3], acc);
        }
        acc.x += __shfl_xor(acc.x, 16, 64); acc.y += __shfl_xor(acc.y, 16, 64);
        acc.z += __shfl_xor(acc.z, 16, 64); acc.w += __shfl_xor(acc.w, 16, 64);
        acc.x += __shfl_xor(acc.x, 32, 64); acc.y += __shfl_xor(acc.y, 32, 64);
        acc.z += __shfl_xor(acc.z, 32, 64); acc.w += __shfl_xor(acc.w, 32, 64);
        if (lane < 16) {
            ushort4 o;
            o.x = f2bf(acc.x); o.y = f2bf(acc.y);
            o.z = f2bf(acc.z); o.w = f2bf(acc.w);
            ((ushort4*)(Y + (size_t)r * D))[c4] = o;   // 8B per lane, 128B per row
        }
    }
}

// ---------------- pull aggregation: one wave per node, bf16 gather payload ----------------
template <int DOTS>
__global__ void agg_kernel(const unsigned short* __restrict__ xw, const float* __restrict__ dinv,
                           const int* __restrict__ off, const int* __restrict__ adj,
                           const float* __restrict__ b, float* __restrict__ out,
                           const float* __restrict__ wlin,
                           float* __restrict__ adot, float* __restrict__ bdot, int n) {
    int wid = blockIdx.x * 4 + (threadIdx.x >> 6);
    if (wid >= n) return;
    int lane = threadIdx.x & 63;
    int l = lane & 15;      // 4-dim chunk of the row
    int g = lane >> 4;      // neighbor slot group 0..3
    int start = (wid == 0) ? 0 : off[wid - 1];
    int end = off[wid];
    int deg = end - start;
    float di = dinv[wid];
    const ushort4* xwb = (const ushort4*)xw;   // row stride = 16 ushort4

    float4 acc = make_float4(0.f, 0.f, 0.f, 0.f);
    if (g == 0) {           // self-loop + bias, added once
        ushort4 u = xwb[(size_t)wid * 16 + l];
        float4 bb = ((const float4*)b)[l];
        float s = di * di;
        acc.x = fmaf(bf2f(u.x), s, bb.x); acc.y = fmaf(bf2f(u.y), s, bb.y);
        acc.z = fmaf(bf2f(u.z), s, bb.z); acc.w = fmaf(bf2f(u.w), s, bb.w);
    }

    for (int base = 0; base < deg; base += 64) {
        // phase 1: cooperative index+scale prefetch (uniform flow before shfl)
        int k = base + lane;
        int a = 0; float s = 0.f;
        if (k < deg) {
            a = adj[start + k];          // coalesced 256B wave load
            s = dinv[a] * di;            // one 4B gather per lane
        }
        int m = min(64, deg - base);
        int mm = (m + 7) & ~7;           // wave-uniform padded bound
        // phase 2: uniform trip count; two independent 128B row gathers per iter
        for (int kk = g; kk < mm; kk += 8) {
            int r0 = __shfl(a, kk, 64);
            int r1 = __shfl(a, kk + 4, 64);
            float s0 = __shfl(s, kk, 64);
            float s1 = __shfl(s, kk + 4, 64);
            ushort4 u0 = xwb[(size_t)r0 * 16 + l];
            ushort4 u1 = xwb[(size_t)r1 * 16 + l];
            acc.x = fmaf(bf2f(u0.x), s0, acc.x); acc.y = fmaf(bf2f(u0.y), s0, acc.y);
            acc.z = fmaf(bf2f(u0.z), s0, acc.z); acc.w = fmaf(bf2f(u0.w), s0, acc.w);
            acc.x = fmaf(bf2f(u1.x), s1, acc.x); acc.y = fmaf(bf2f(u1.y), s1, acc.y);
            acc.z = fmaf(bf2f(u1.z), s1, acc.z); acc.w = fmaf(bf2f(u1.w), s1, acc.w);
        }
    }
    // reduce across the 4 neighbor-slot groups
    acc.x += __shfl_xor(acc.x, 16, 64); acc.y += __shfl_xor(acc.y, 16, 64);
    acc.z += __shfl_xor(acc.z, 16, 64); acc.w += __shfl_xor(acc.w, 16, 64);
    acc.x += __shfl_xor(acc.x, 32, 64); acc.y += __shfl_xor(acc.y, 32, 64);
    acc.z += __shfl_xor(acc.z, 32, 64); acc.w += __shfl_xor(acc.w, 32, 64);

    if (DOTS) {
        float4 hv = acc;
        hv.x = fmaxf(hv.x, 0.f); hv.y = fmaxf(hv.y, 0.f);
        hv.z = fmaxf(hv.z, 0.f); hv.w = fmaxf(hv.w, 0.f);
        float4 wa = ((const float4*)wlin)[l];
        float4 wb = ((const float4*)wlin)[16 + l];
        float pa = hv.x * wa.x + hv.y * wa.y + hv.z * wa.z + hv.w * wa.w;
        float pb = hv.x * wb.x + hv.y * wb.y + hv.z * wb.z + hv.w * wb.w;
        #pragma unroll
        for (int o = 8; o > 0; o >>= 1) {
            pa += __shfl_xor(pa, o, 64);
            pb += __shfl_xor(pb, o, 64);
        }
        if (lane == 0) { adot[wid] = pa; bdot[wid] = pb; }
    } else {
        if (lane < 16)
            ((float4*)(out + (size_t)wid * D))[l] = acc;
    }
}

// ---------------- edge output: sigmoid(adot[row] + bdot[col] + blin) ----------------
__global__ void edge_out_kernel(const int* __restrict__ row, const int* __restrict__ col,
                                const float* __restrict__ adot, const float* __restrict__ bdot,
                                const float* __restrict__ blin, float* __restrict__ out, int E) {
    int e = blockIdx.x * blockDim.x + threadIdx.x;
    if (e >= E) return;
    float z = adot[row[e]] + bdot[col[e]] + blin[0];
    out[e] = 1.f / (1.f + expf(-z));
}

// ---------------- launch ----------------
extern "C" void kernel_launch(void* const* d_in, const int* in_sizes, int n_in,
                              void* d_out, int out_size, void* d_ws, size_t ws_size,
                              hipStream_t stream) {
    const float* x     = (const float*)d_in[0];
    const int*   ei    = (const int*)d_in[1];
    const float* w1    = (const float*)d_in[2];
    const float* b1    = (const float*)d_in[3];
    const float* w2    = (const float*)d_in[4];
    const float* b2    = (const float*)d_in[5];
    const float* w_lin = (const float*)d_in[6];
    const float* b_lin = (const float*)d_in[7];
    float* out = (float*)d_out;

    int n = in_sizes[0] / D;        // 100000
    int E = in_sizes[1] / 2;        // 1000000
    const int* row = ei;
    const int* col = ei + E;

    int NB = (n + (1 << NB_SHIFT) - 1) >> NB_SHIFT;   // 196 buckets of 512 nodes
    int B  = NB;                                      // partition blocks = buckets
    int CH = (E + B - 1) / B;                         // edges per chunk
    int NBB = NB * B;                                 // histogram entries (38416)
    int nScanBlocks = (NBB + SCAN_TILE - 1) / SCAN_TILE;   // 38 (<=256)

    // ---- workspace bump allocator (256B aligned) ----
    char* ws = (char*)d_ws;
    size_t cur = 0;
    auto alloc = [&](size_t bytes) -> void* {
        void* p = ws + cur;
        cur += (bytes + 255) / 256 * 256;
        return p;
    };
    int*            histG = (int*)   alloc((size_t)NBB * sizeof(int));
    int*            scanH = (int*)   alloc((size_t)NBB * sizeof(int));
    int*            bsums = (int*)   alloc((size_t)nScanBlocks * sizeof(int));
    int2*           pairs = (int2*)  alloc((size_t)E * sizeof(int2));
    int*            off   = (int*)   alloc((size_t)n * sizeof(int));
    float*          dinv  = (float*) alloc((size_t)n * sizeof(float));
    int*            adj   = (int*)   alloc((size_t)E * sizeof(int));
    float*          adot  = (float*) alloc((size_t)n * sizeof(float));
    float*          bdot  = (float*) alloc((size_t)n * sizeof(float));
    unsigned short* bufA  = (unsigned short*)alloc((size_t)n * D * sizeof(unsigned short)); // xw bf16
    float*          bufB  = (float*) alloc((size_t)n * D * sizeof(float));                  // h1 f32

    const int BT = 256;
    int gE    = (E + BT - 1) / BT;
    int gWave = (n + 3) / 4;                      // 4 waves (nodes) per block
    int gGemm = 1024;                             // grid-stride GEMM

    // ---- atomic-free CSR build ----
    hist_kernel<<<B, BT, 0, stream>>>(col, histG, E, B, NB, CH);
    block_reduce_kernel<<<nScanBlocks, SCAN_BLOCK, 0, stream>>>(histG, bsums, NBB);
    scan_sums_kernel<<<1, 256, 0, stream>>>(bsums, nScanBlocks);
    scan_apply_kernel<<<nScanBlocks, SCAN_BLOCK, 0, stream>>>(histG, bsums, scanH, nullptr, NBB);
    scatter_pairs_kernel<<<B, BT, 0, stream>>>(row, col, scanH, pairs, E, B, NB, CH);
    bucket_csr_kernel<<<NB, BT, 0, stream>>>(pairs, scanH, off, dinv, adj, E, B, NB, n);
    // off[i] = inclusive end of node i's adjacency; start = off[i-1] (0 for i=0)

    // ---- layer 1: h1 = agg(x @ w1) + b1  (relu deferred to next load) ----
    gemm64_reg_kernel<<<gGemm, BT, 0, stream>>>(x, w1, bufA, n, 0);
    agg_kernel<0><<<gWave, BT, 0, stream>>>(bufA, dinv, off, adj, b1, bufB,
                                            nullptr, nullptr, nullptr, n);

    // ---- layer 2: xw2 = relu(h1) @ w2; agg fused with edge-head node dots ----
    gemm64_reg_kernel<<<gGemm, BT, 0, stream>>>(bufB, w2, bufA, n, 1);
    agg_kernel<1><<<gWave, BT, 0, stream>>>(bufA, dinv, off, adj, b2, nullptr,
                                            w_lin, adot, bdot, n);

    // ---- edge prediction head ----
    edge_out_kernel<<<gE, BT, 0, stream>>>(row, col, adot, bdot, b_lin, out, E);
}